// Round 3
// baseline (1039.095 us; speedup 1.0000x reference)
//
#include <hip/hip_runtime.h>
#include <hip/hip_bf16.h>

typedef __hip_bfloat16 bf16;

#define B_  8
#define C_  64
#define H_  128
#define W_  128
#define HW_ (H_*W_)
#define TH  16
#define TW  16
#define CCH 8    // cin chunk for LDS staging

static __device__ __forceinline__ float ldf(const float* p, size_t i) { return p[i]; }
static __device__ __forceinline__ float ldf(const bf16*  p, size_t i) { return __bfloat162float(p[i]); }
static __device__ __forceinline__ void  stf(float* p, size_t i, float v) { p[i] = v; }
static __device__ __forceinline__ void  stf(bf16*  p, size_t i, float v) { p[i] = __float2bfloat16(v); }

// ---------------- 3x3 conv, optionally pixel-adaptive (fused gaussian kern) --
// out[b,o,h,w] = act( bias[o] + sum_{c,p} in[b,c,h+di-1,w+dj-1]
//                                        * (PAC ? exp(-0.5*||g_patch-g_ctr||^2) : 1)
//                                        * w[o,c,p] )  (+ resid if RESID)
// block: 16x16 pixel tile, all 64 out channels. 256 threads =
//   4 out-channel groups (1 wave each) x 64 pixel-threads x 4 rows each.
template<typename TIN, typename TG, typename TOUT, bool PAC, bool RELU, bool RESID>
__global__ __launch_bounds__(256) void conv3x3_kernel(
    const TIN* __restrict__ in, const float* __restrict__ wgt,
    const float* __restrict__ bias, const TG* __restrict__ guide,
    const float* __restrict__ resid, TOUT* __restrict__ out)
{
    __shared__ float s_x[CCH][TH+2][TW+4];      // [8][18][20]
    __shared__ float s_w[CCH*9][64];            // [c*9+p][o]
    __shared__ float s_k[PAC ? 9 : 1][TH][TW];  // adaptive kernel per tile

    const int t    = threadIdx.x;
    const int b    = blockIdx.y;
    const int th0  = (blockIdx.x >> 3) * TH;
    const int tw0  = (blockIdx.x & 7) * TW;
    const int og   = t >> 6;          // out-channel group == wave id
    const int pid  = t & 63;
    const int px   = pid & 15;
    const int row0 = (pid >> 4) * 4;  // this thread's 4 rows

    // ---- PAC pre-pass: compute adaptive kernel for this tile into s_k ----
    if (PAC) {
        float d2[36];                 // [p][q] flattened
#pragma unroll
        for (int i = 0; i < 36; ++i) d2[i] = 0.f;

#pragma unroll 1
        for (int c0 = 0; c0 < C_; c0 += CCH) {
            __syncthreads();
            for (int i = t; i < CCH*18*18; i += 256) {
                int c = i / 324, rem = i % 324;
                int r = rem / 18, cc = rem % 18;
                int gh = th0 + r - 1, gw = tw0 + cc - 1;
                float v = 0.f;
                if (gh >= 0 && gh < H_ && gw >= 0 && gw < W_)
                    v = ldf(guide, ((size_t)b*C_ + c0 + c)*HW_ + gh*W_ + gw);
                s_x[c][r][cc] = v;
            }
            __syncthreads();
#pragma unroll
            for (int c = 0; c < CCH; ++c) {
#pragma unroll
                for (int q = 0; q < 4; ++q) {
                    float xc = s_x[c][row0 + q + 1][px + 1];
#pragma unroll
                    for (int p = 0; p < 9; ++p) {
                        float d = s_x[c][row0 + q + p/3][px + p%3] - xc;
                        d2[p*4 + q] += d * d;
                    }
                }
            }
        }
        // every wave computed the full d2 (redundant); wave 0 publishes.
        if (og == 0) {
#pragma unroll
            for (int p = 0; p < 9; ++p)
#pragma unroll
                for (int q = 0; q < 4; ++q)
                    s_k[p][row0 + q][px] = __expf(-0.5f * d2[p*4 + q]);
        }
        // visibility of s_k: first main-loop __syncthreads() orders it.
    }

    float acc[4][16];
#pragma unroll
    for (int o = 0; o < 16; ++o) {
        float bv = bias[og*16 + o];
#pragma unroll
        for (int q = 0; q < 4; ++q) acc[q][o] = bv;
    }

#pragma unroll 1
    for (int c0 = 0; c0 < C_; c0 += CCH) {
        __syncthreads();
        for (int i = t; i < CCH*18*18; i += 256) {
            int c = i / 324, rem = i % 324;
            int r = rem / 18, cc = rem % 18;
            int gh = th0 + r - 1, gw = tw0 + cc - 1;
            float v = 0.f;
            if (gh >= 0 && gh < H_ && gw >= 0 && gw < W_)
                v = ldf(in, ((size_t)b*C_ + c0 + c)*HW_ + gh*W_ + gw);
            s_x[c][r][cc] = v;
        }
        for (int i = t; i < CCH*9*64; i += 256) {
            int o = i & 63, cp = i >> 6;
            s_w[cp][o] = wgt[(size_t)o*(C_*9) + (size_t)c0*9 + cp];
        }
        __syncthreads();

#pragma unroll 1
        for (int p = 0; p < 9; ++p) {
            const int di = p / 3, dj = p % 3;
            float kv[4];
            if (PAC) {
#pragma unroll
                for (int q = 0; q < 4; ++q) kv[q] = s_k[p][row0 + q][px];
            }
#pragma unroll
            for (int c = 0; c < CCH; ++c) {
                const float* wr = &s_w[c*9 + p][og*16];
                float4 w0 = *(const float4*)(wr);
                float4 w1 = *(const float4*)(wr + 4);
                float4 w2 = *(const float4*)(wr + 8);
                float4 w3 = *(const float4*)(wr + 12);
                float xk[4];
#pragma unroll
                for (int q = 0; q < 4; ++q) {
                    float xv = s_x[c][row0 + q + di][px + dj];
                    xk[q] = PAC ? xv * kv[q] : xv;
                }
#pragma unroll
                for (int q = 0; q < 4; ++q) {
                    acc[q][0]  += xk[q]*w0.x; acc[q][1]  += xk[q]*w0.y;
                    acc[q][2]  += xk[q]*w0.z; acc[q][3]  += xk[q]*w0.w;
                    acc[q][4]  += xk[q]*w1.x; acc[q][5]  += xk[q]*w1.y;
                    acc[q][6]  += xk[q]*w1.z; acc[q][7]  += xk[q]*w1.w;
                    acc[q][8]  += xk[q]*w2.x; acc[q][9]  += xk[q]*w2.y;
                    acc[q][10] += xk[q]*w2.z; acc[q][11] += xk[q]*w2.w;
                    acc[q][12] += xk[q]*w3.x; acc[q][13] += xk[q]*w3.y;
                    acc[q][14] += xk[q]*w3.z; acc[q][15] += xk[q]*w3.w;
                }
            }
        }
    }

    const size_t obase = ((size_t)b*C_ + og*16)*HW_ + (size_t)th0*W_ + tw0;
#pragma unroll
    for (int o = 0; o < 16; ++o) {
#pragma unroll
        for (int q = 0; q < 4; ++q) {
            float v = acc[q][o];
            if (RELU) v = fmaxf(v, 0.f);
            size_t idx = obase + (size_t)o*HW_ + (size_t)(row0 + q)*W_ + px;
            if (RESID) v += resid[idx];
            stf(out, idx, v);
        }
    }
}

extern "C" void kernel_launch(void* const* d_in, const int* in_sizes, int n_in,
                              void* d_out, int out_size, void* d_ws, size_t ws_size,
                              hipStream_t stream)
{
    // Reference dtypes are all float32 -> cast per harness contract.
    const float* x      = (const float*)d_in[0];
    const float* edge   = (const float*)d_in[1];
    const float* w_pac1 = (const float*)d_in[2];
    const float* b_pac1 = (const float*)d_in[3];
    const float* w_pac2 = (const float*)d_in[4];
    const float* b_pac2 = (const float*)d_in[5];
    const float* w_e1   = (const float*)d_in[6];
    const float* b_e1   = (const float*)d_in[7];
    const float* w_e2   = (const float*)d_in[8];
    const float* b_e2   = (const float*)d_in[9];

    float* out_sr   = (float*)d_out;                 // [B,C,H,W] f32
    float* out_edge = out_sr + (size_t)B_*C_*HW_;    // [B,C,H,W] f32

    // Scratch: res_edge1 in d_ws as bf16 (16.8 MB — minimal footprint);
    // res_sr1 parks as f32 in the out_edge half of d_out (dead until launch 4).
    bf16*  res_edge1 = (bf16*)d_ws;
    float* res_sr1   = out_edge;

    dim3 grid((H_/TH)*(W_/TW), B_), blk(256);

    // 1) res_edge1 = relu(conv(edge, w_e1) + b_e1)          [bf16 -> ws]
    conv3x3_kernel<float, float, bf16,  false, true,  false><<<grid, blk, 0, stream>>>(
        edge, w_e1, b_e1, (const float*)nullptr, nullptr, res_edge1);
    // 2) res_sr1 = relu(pac(x | guide=edge, w_pac1) + b_pac1)   [f32 -> out_edge slot]
    conv3x3_kernel<float, float, float, true,  true,  false><<<grid, blk, 0, stream>>>(
        x, w_pac1, b_pac1, edge, nullptr, res_sr1);
    // 3) out_sr = x + pac(res_sr1 | guide=res_edge1, w_pac2) + b_pac2
    conv3x3_kernel<float, bf16,  float, true,  false, true ><<<grid, blk, 0, stream>>>(
        res_sr1, w_pac2, b_pac2, res_edge1, x, out_sr);
    // 4) out_edge = edge + conv(res_edge1, w_e2) + b_e2   (overwrites dead res_sr1)
    conv3x3_kernel<bf16,  float, float, false, false, true ><<<grid, blk, 0, stream>>>(
        res_edge1, w_e2, b_e2, (const float*)nullptr, edge, out_edge);
}

// Round 4
// 291.300 us; speedup vs baseline: 3.5671x; 3.5671x over previous
//
#include <hip/hip_runtime.h>
#include <hip/hip_bf16.h>

typedef __attribute__((ext_vector_type(8))) short s8;   // 8 bf16 (4 VGPR) MFMA frag
typedef __attribute__((ext_vector_type(4))) float f4;   // 4 f32 acc frag

#define B_  8
#define C_  64
#define H_  128
#define W_  128
#define HW_ (H_*W_)
#define PITCH 72   // LDS c-pitch in shorts: 144B/pixel-row -> 16B-aligned, exactly 2-way bank aliasing (free)

// f32 -> bf16 bits, round-to-nearest-even (finite inputs only)
static __device__ __forceinline__ unsigned short f2bu(float f) {
    union { float f; unsigned u; } c; c.f = f;
    unsigned u = c.u;
    u += 0x7fffu + ((u >> 16) & 1u);
    return (unsigned short)(u >> 16);
}
static __device__ __forceinline__ float bu2f(unsigned short u) {
    union { unsigned u; float f; } c; c.u = ((unsigned)u) << 16; return c.f;
}

// ---------- transpose+cast: [b][c][h][w] f32 -> [b][h][w][c] bf16 (x and edge in one grid) ----------
__global__ __launch_bounds__(256) void transpose2(
    const float* __restrict__ x, const float* __restrict__ edge,
    unsigned short* __restrict__ x_t, unsigned short* __restrict__ edge_t)
{
    __shared__ float s[16][68];   // 272B rows: 16B-aligned, 2-way max aliasing
    const int t  = threadIdx.x;
    const int h  = blockIdx.x >> 3;
    const int w0 = (blockIdx.x & 7) * 16;
    const int b  = blockIdx.y;
    const float* src = blockIdx.z ? edge : x;
    unsigned short* dst = blockIdx.z ? edge_t : x_t;
    {
        int c = t >> 2, wq = t & 3;
        float4 v = *(const float4*)(src + ((size_t)b*C_ + c)*HW_ + h*W_ + w0 + wq*4);
        s[wq*4+0][c] = v.x; s[wq*4+1][c] = v.y; s[wq*4+2][c] = v.z; s[wq*4+3][c] = v.w;
    }
    __syncthreads();
    {
        int w = t >> 4, cg = t & 15;
        float4 v = *(const float4*)(&s[w][cg*4]);
        ushort4 o; o.x = f2bu(v.x); o.y = f2bu(v.y); o.z = f2bu(v.z); o.w = f2bu(v.w);
        *(ushort4*)(dst + ((size_t)b*HW_ + h*W_ + w0 + w)*64 + cg*4) = o;
    }
}

// ---------- weight transform: [o][c][3][3] f32 -> [p][o][c] bf16 ----------
__global__ __launch_bounds__(256) void wt_kernel(
    const float* __restrict__ w, unsigned short* __restrict__ dst)
{
    int idx = blockIdx.x*256 + threadIdx.x;     // 9*64*64 = 36864
    int p = idx >> 12, o = (idx >> 6) & 63, c = idx & 63;
    dst[idx] = f2bu(w[((size_t)o*64 + c)*9 + p]);
}

// ---------- adaptive gaussian kernel from transposed guide ----------
// kern[b][p][hw] = exp(-0.5 * sum_c (g[pix+off(p)][c] - g[pix][c])^2), zero-padded
__global__ __launch_bounds__(256, 2) void gauss_kern(
    const unsigned short* __restrict__ g_t,   // [b][hw][64] bf16
    float* __restrict__ kern)                 // [b][9][hw] f32
{
    __shared__ unsigned short s_g[18*18*PITCH];
    const int t   = threadIdx.x;
    const int b   = blockIdx.y;
    const int th0 = (blockIdx.x >> 3) * 16;
    const int tw0 = (blockIdx.x & 7) * 16;

    for (int i = t; i < 18*18*8; i += 256) {
        int pix = i >> 3, ch = i & 7;
        int rr = pix / 18, ww = pix - rr*18;
        int gr = th0 + rr - 1, gw = tw0 + ww - 1;
        uint4 v = {0u,0u,0u,0u};
        if ((unsigned)gr < (unsigned)H_ && (unsigned)gw < (unsigned)W_)
            v = *(const uint4*)(g_t + ((size_t)b*HW_ + gr*W_ + gw)*64 + ch*8);
        *(uint4*)(&s_g[pix*PITCH + ch*8]) = v;
    }
    __syncthreads();

    const int px = t & 15, py = t >> 4;
    float d2[9];
#pragma unroll
    for (int p = 0; p < 9; ++p) d2[p] = 0.f;

    const unsigned short* cb = &s_g[((py+1)*18 + (px+1))*PITCH];
#pragma unroll 1
    for (int co = 0; co < 8; ++co) {
        s8 c8 = *(const s8*)(cb + co*8);
        float cf[8];
#pragma unroll
        for (int j = 0; j < 8; ++j) cf[j] = bu2f((unsigned short)c8[j]);
#pragma unroll
        for (int p = 0; p < 9; ++p) {
            s8 n8 = *(const s8*)(&s_g[((py + p/3)*18 + px + p%3)*PITCH + co*8]);
#pragma unroll
            for (int j = 0; j < 8; ++j) {
                float d = bu2f((unsigned short)n8[j]) - cf[j];
                d2[p] += d * d;
            }
        }
    }
#pragma unroll
    for (int p = 0; p < 9; ++p)
        kern[(((size_t)b*9 + p) << 14) + (th0+py)*W_ + tw0 + px] = __expf(-0.5f * d2[p]);
}

// ---------- MFMA implicit-GEMM 3x3 conv ----------
// Per block: batch b, 16x16 pixel tile, all 64 out-ch. 4 waves; wave wv owns rows wv*4..+3.
// out = bias + sum_p [ kern_p ⊙ ] (W_p[64,64c] x X_shift(p)[64c,256pix])  (+resid / relu)
template<bool PAC, bool RELU, bool TROUT>
__global__ __launch_bounds__(256, 2) void mfma_conv(
    const unsigned short* __restrict__ in_t,   // [b][hw][64] bf16
    const unsigned short* __restrict__ w_t,    // [9][64][64] bf16 (this conv)
    const float* __restrict__ bias,
    const float* __restrict__ kern,            // [b][9][hw] f32 (PAC only)
    const float* __restrict__ resid,           // natural f32 (!TROUT only)
    void* __restrict__ outp)                   // TROUT: ushort [b][hw][64]; else float [b][64][hw]
{
    __shared__ unsigned short s_x[18*18*PITCH];

    const int t    = threadIdx.x;
    const int b    = blockIdx.y;
    const int th0  = (blockIdx.x >> 3) * 16;
    const int tw0  = (blockIdx.x & 7) * 16;
    const int wv   = t >> 6;
    const int lane = t & 63;
    const int ln   = lane & 15;    // n (pixel col) within frag
    const int quad = lane >> 4;

    // stage 18x18 pixel tile (64c contiguous per pixel), zero-padded halo
    for (int i = t; i < 18*18*8; i += 256) {
        int pix = i >> 3, ch = i & 7;
        int rr = pix / 18, ww = pix - rr*18;
        int gr = th0 + rr - 1, gw = tw0 + ww - 1;
        uint4 v = {0u,0u,0u,0u};
        if ((unsigned)gr < (unsigned)H_ && (unsigned)gw < (unsigned)W_)
            v = *(const uint4*)(in_t + ((size_t)b*HW_ + gr*W_ + gw)*64 + ch*8);
        *(uint4*)(&s_x[pix*PITCH + ch*8]) = v;
    }
    __syncthreads();

    f4 acc[4][4];
#pragma unroll
    for (int mf = 0; mf < 4; ++mf) {
        f4 bv;
#pragma unroll
        for (int r = 0; r < 4; ++r) bv[r] = bias[mf*16 + quad*4 + r];
#pragma unroll
        for (int nf = 0; nf < 4; ++nf) acc[mf][nf] = bv;
    }

#pragma unroll 1
    for (int p = 0; p < 9; ++p) {
        const int dr = p / 3, dc = p - dr*3;
        // A-frags from global (L2-hot): A[m=lane&15][k=quad*8+j], k=c
        s8 a[4][2];
#pragma unroll
        for (int mf = 0; mf < 4; ++mf)
#pragma unroll
            for (int kc = 0; kc < 2; ++kc)
                a[mf][kc] = *(const s8*)(w_t + (((size_t)p*64 + mf*16 + ln)*64 + kc*32 + quad*8));
        // B-frags from LDS: B[k=quad*8+j][n=lane&15], single b128 each
        s8 bfr[4][2];
#pragma unroll
        for (int nf = 0; nf < 4; ++nf) {
            const unsigned short* base = &s_x[((wv*4 + nf + dr)*18 + ln + dc)*PITCH];
#pragma unroll
            for (int kc = 0; kc < 2; ++kc)
                bfr[nf][kc] = *(const s8*)(base + kc*32 + quad*8);
        }
        float kv[4];
        if (PAC) {
#pragma unroll
            for (int nf = 0; nf < 4; ++nf)
                kv[nf] = kern[(((size_t)b*9 + p) << 14) + (th0 + wv*4 + nf)*W_ + tw0 + ln];
        }
#pragma unroll
        for (int mf = 0; mf < 4; ++mf)
#pragma unroll
            for (int nf = 0; nf < 4; ++nf) {
                if (PAC) {
                    f4 d = {0.f, 0.f, 0.f, 0.f};
                    d = __builtin_amdgcn_mfma_f32_16x16x32_bf16(a[mf][0], bfr[nf][0], d, 0, 0, 0);
                    d = __builtin_amdgcn_mfma_f32_16x16x32_bf16(a[mf][1], bfr[nf][1], d, 0, 0, 0);
                    acc[mf][nf] += kv[nf] * d;   // VALU fold (separate pipe from MFMA)
                } else {
                    acc[mf][nf] = __builtin_amdgcn_mfma_f32_16x16x32_bf16(a[mf][0], bfr[nf][0], acc[mf][nf], 0, 0, 0);
                    acc[mf][nf] = __builtin_amdgcn_mfma_f32_16x16x32_bf16(a[mf][1], bfr[nf][1], acc[mf][nf], 0, 0, 0);
                }
            }
    }

    // epilogue: D[m=quad*4+reg][n=lane&15]
    if (TROUT) {
        unsigned short* out = (unsigned short*)outp;
#pragma unroll
        for (int mf = 0; mf < 4; ++mf)
#pragma unroll
            for (int nf = 0; nf < 4; ++nf) {
                f4 v = acc[mf][nf];
                if (RELU) {
#pragma unroll
                    for (int r = 0; r < 4; ++r) v[r] = fmaxf(v[r], 0.f);
                }
                size_t pix = (size_t)b*HW_ + (th0 + wv*4 + nf)*W_ + tw0 + ln;
                ushort4 o; o.x = f2bu(v[0]); o.y = f2bu(v[1]); o.z = f2bu(v[2]); o.w = f2bu(v[3]);
                *(ushort4*)(out + pix*64 + mf*16 + quad*4) = o;
            }
    } else {
        float* out = (float*)outp;
#pragma unroll
        for (int mf = 0; mf < 4; ++mf)
#pragma unroll
            for (int nf = 0; nf < 4; ++nf)
#pragma unroll
                for (int r = 0; r < 4; ++r) {
                    int och = mf*16 + quad*4 + r;
                    size_t idx = ((size_t)b*C_ + och)*HW_ + (th0 + wv*4 + nf)*W_ + tw0 + ln;
                    float v = acc[mf][nf][r];
                    if (RELU) v = fmaxf(v, 0.f);
                    out[idx] = v + resid[idx];
                }
    }
}

extern "C" void kernel_launch(void* const* d_in, const int* in_sizes, int n_in,
                              void* d_out, int out_size, void* d_ws, size_t ws_size,
                              hipStream_t stream)
{
    const float* x      = (const float*)d_in[0];
    const float* edge   = (const float*)d_in[1];
    const float* w_pac1 = (const float*)d_in[2];
    const float* b_pac1 = (const float*)d_in[3];
    const float* w_pac2 = (const float*)d_in[4];
    const float* b_pac2 = (const float*)d_in[5];
    const float* w_e1   = (const float*)d_in[6];
    const float* b_e1   = (const float*)d_in[7];
    const float* w_e2   = (const float*)d_in[8];
    const float* b_e2   = (const float*)d_in[9];

    float* out_sr   = (float*)d_out;
    float* out_edge = out_sr + (size_t)B_*C_*HW_;

    const size_t NT = (size_t)B_*HW_*64;   // elems of a transposed tensor (bf16)

    // ws (21.8 MB): res_edge1_t | kern f32 | w_t[4]
    unsigned short* res_edge1_t = (unsigned short*)d_ws;
    float*          kerb        = (float*)((char*)d_ws + NT*2);
    unsigned short* w_t         = (unsigned short*)(kerb + (size_t)B_*9*HW_);
    // parked in d_out (dead regions until final writes):
    unsigned short* edge_t    = (unsigned short*)out_sr;           // dead after conv_e1
    unsigned short* x_t       = (unsigned short*)out_edge;         // dead after conv_pac1
    unsigned short* res_sr1_t = x_t + NT;                          // dead after conv_pac2

    dim3 blk(256), cgrid(64, B_);

    transpose2<<<dim3(H_*8, B_, 2), blk, 0, stream>>>(x, edge, x_t, edge_t);
    wt_kernel<<<144, blk, 0, stream>>>(w_pac1, w_t + 0*36864);
    wt_kernel<<<144, blk, 0, stream>>>(w_e1,   w_t + 1*36864);
    wt_kernel<<<144, blk, 0, stream>>>(w_pac2, w_t + 2*36864);
    wt_kernel<<<144, blk, 0, stream>>>(w_e2,   w_t + 3*36864);

    gauss_kern<<<cgrid, blk, 0, stream>>>(edge_t, kerb);                       // kern1(edge)
    mfma_conv<false, true,  true ><<<cgrid, blk, 0, stream>>>(                 // res_edge1
        edge_t, w_t + 1*36864, b_e1, nullptr, nullptr, res_edge1_t);
    mfma_conv<true,  true,  true ><<<cgrid, blk, 0, stream>>>(                 // res_sr1
        x_t, w_t + 0*36864, b_pac1, kerb, nullptr, res_sr1_t);
    gauss_kern<<<cgrid, blk, 0, stream>>>(res_edge1_t, kerb);                  // kern2(res_edge1)
    mfma_conv<true,  false, false><<<cgrid, blk, 0, stream>>>(                 // out_sr = x + pac2
        res_sr1_t, w_t + 2*36864, b_pac2, kerb, x, out_sr);
    mfma_conv<false, false, false><<<cgrid, blk, 0, stream>>>(                 // out_edge = edge + conv
        res_edge1_t, w_t + 3*36864, b_e2, nullptr, edge, out_edge);
}

// Round 5
// 263.900 us; speedup vs baseline: 3.9375x; 1.1038x over previous
//
#include <hip/hip_runtime.h>

typedef unsigned short u16;
typedef __attribute__((ext_vector_type(8))) short s8;   // 8 bf16 (4 VGPR) MFMA frag
typedef __attribute__((ext_vector_type(4))) float f4;   // 4 f32 acc frag

#define B_  8
#define C_  64
#define H_  128
#define W_  128
#define HW_ (H_*W_)
#define PITCH 72     // LDS shorts per pixel (144 B rows, 16B-aligned, uniform bank spread)
#define WSZ 36864    // elems of one transformed weight tensor [9][64][64]

// f32 -> bf16 bits, round-to-nearest-even (finite only)
static __device__ __forceinline__ u16 f2bu(float f) {
    union { float f; unsigned u; } c; c.f = f;
    unsigned u = c.u;
    u += 0x7fffu + ((u >> 16) & 1u);
    return (u16)(u >> 16);
}
static __device__ __forceinline__ float bu2f(u16 u) {
    union { unsigned u; float f; } c; c.u = ((unsigned)u) << 16; return c.f;
}

// ---------- transpose+cast: [b][c][h][w] f32 -> [b][h][w][c] bf16 ----------
__global__ __launch_bounds__(256) void transpose2(
    const float* __restrict__ x, const float* __restrict__ edge,
    u16* __restrict__ x_t, u16* __restrict__ edge_t)
{
    __shared__ float s[16][68];
    const int t  = threadIdx.x;
    const int h  = blockIdx.x >> 3;
    const int w0 = (blockIdx.x & 7) * 16;
    const int b  = blockIdx.y;
    const float* src = blockIdx.z ? edge : x;
    u16* dst = blockIdx.z ? edge_t : x_t;
    {
        int c = t >> 2, wq = t & 3;
        float4 v = *(const float4*)(src + ((size_t)b*C_ + c)*HW_ + h*W_ + w0 + wq*4);
        s[wq*4+0][c] = v.x; s[wq*4+1][c] = v.y; s[wq*4+2][c] = v.z; s[wq*4+3][c] = v.w;
    }
    __syncthreads();
    {
        int w = t >> 4, cg = t & 15;
        float4 v = *(const float4*)(&s[w][cg*4]);
        ushort4 o; o.x = f2bu(v.x); o.y = f2bu(v.y); o.z = f2bu(v.z); o.w = f2bu(v.w);
        *(ushort4*)(dst + ((size_t)b*HW_ + h*W_ + w0 + w)*64 + cg*4) = o;
    }
}

// ---------- weight transform: 4x [o][c][3][3] f32 -> [cid][p][o][c] bf16 ----------
__global__ __launch_bounds__(256) void wt_all(
    const float* __restrict__ w0, const float* __restrict__ w1,
    const float* __restrict__ w2, const float* __restrict__ w3,
    u16* __restrict__ dst)
{
    int idx = blockIdx.x*256 + threadIdx.x;            // 0..36863
    int cid = blockIdx.y;
    const float* w = (cid == 0) ? w0 : (cid == 1) ? w1 : (cid == 2) ? w2 : w3;
    int p = idx >> 12, o = (idx >> 6) & 63, c = idx & 63;
    dst[(size_t)cid*WSZ + idx] = f2bu(w[((size_t)o*64 + c)*9 + p]);
}

// ---------- helpers for the fused kernel ----------
static __device__ __forceinline__ void stage_tile(
    u16* __restrict__ s_t, const u16* __restrict__ src, int b, int th0, int tw0, int t)
{
    for (int i = t; i < 18*18*8; i += 256) {
        int pix = i >> 3, ch = i & 7;
        int rr = pix / 18, ww = pix - rr*18;
        int gr = th0 + rr - 1, gw = tw0 + ww - 1;
        uint4 v = {0u,0u,0u,0u};
        if ((unsigned)gr < (unsigned)H_ && (unsigned)gw < (unsigned)W_)
            v = *(const uint4*)(src + ((size_t)b*HW_ + gr*W_ + gw)*64 + ch*8);
        *(uint4*)(&s_t[pix*PITCH + ch*8]) = v;
    }
}

// conv core: D = sum_p [kern_p ⊙] W_p[64och,64c] x X_p[64c,256px], f32 acc, bias init.
// wave wv owns pixel rows wv*4+nf; frag maps verified in round 4.
template<bool PAC>
static __device__ __forceinline__ void conv_core(
    const u16* __restrict__ s_t, const float* __restrict__ s_k,
    const u16* __restrict__ w, const float* __restrict__ bias,
    f4 acc[4][4], int wv, int ln, int quad)
{
#pragma unroll
    for (int mf = 0; mf < 4; ++mf) {
        f4 bv;
#pragma unroll
        for (int r = 0; r < 4; ++r) bv[r] = bias[mf*16 + quad*4 + r];
#pragma unroll
        for (int nf = 0; nf < 4; ++nf) acc[mf][nf] = bv;
    }

#pragma unroll
    for (int p = 0; p < 9; ++p) {
        const int dr = p / 3, dc = p - dr*3;
        s8 a[4][2];
#pragma unroll
        for (int mf = 0; mf < 4; ++mf)
#pragma unroll
            for (int kc = 0; kc < 2; ++kc)
                a[mf][kc] = *(const s8*)(w + (((size_t)p*64 + mf*16 + ln)*64 + kc*32 + quad*8));
        s8 bfr[4][2];
#pragma unroll
        for (int nf = 0; nf < 4; ++nf) {
            const u16* base = &s_t[((wv*4 + nf + dr)*18 + ln + dc)*PITCH];
#pragma unroll
            for (int kc = 0; kc < 2; ++kc)
                bfr[nf][kc] = *(const s8*)(base + kc*32 + quad*8);
        }
        if (PAC) {
            float kv[4];
#pragma unroll
            for (int nf = 0; nf < 4; ++nf)
                kv[nf] = s_k[p*256 + (wv*4 + nf)*16 + ln];
#pragma unroll
            for (int mf = 0; mf < 4; ++mf)
#pragma unroll
                for (int nf = 0; nf < 4; ++nf) {
                    f4 d = {0.f, 0.f, 0.f, 0.f};
                    d = __builtin_amdgcn_mfma_f32_16x16x32_bf16(a[mf][0], bfr[nf][0], d, 0, 0, 0);
                    d = __builtin_amdgcn_mfma_f32_16x16x32_bf16(a[mf][1], bfr[nf][1], d, 0, 0, 0);
                    acc[mf][nf] += kv[nf] * d;
                }
        } else {
#pragma unroll
            for (int mf = 0; mf < 4; ++mf)
#pragma unroll
                for (int nf = 0; nf < 4; ++nf) {
                    acc[mf][nf] = __builtin_amdgcn_mfma_f32_16x16x32_bf16(a[mf][0], bfr[nf][0], acc[mf][nf], 0, 0, 0);
                    acc[mf][nf] = __builtin_amdgcn_mfma_f32_16x16x32_bf16(a[mf][1], bfr[nf][1], acc[mf][nf], 0, 0, 0);
                }
        }
    }
}

// epilogue: bf16 NHWC with relu (stage 1)
static __device__ __forceinline__ void store_t(
    u16* __restrict__ out, f4 acc[4][4], int b, int th0, int tw0, int wv, int ln, int quad)
{
#pragma unroll
    for (int mf = 0; mf < 4; ++mf)
#pragma unroll
        for (int nf = 0; nf < 4; ++nf) {
            f4 v = acc[mf][nf];
            ushort4 o;
            o.x = f2bu(fmaxf(v[0], 0.f)); o.y = f2bu(fmaxf(v[1], 0.f));
            o.z = f2bu(fmaxf(v[2], 0.f)); o.w = f2bu(fmaxf(v[3], 0.f));
            size_t pix = (size_t)b*HW_ + (th0 + wv*4 + nf)*W_ + tw0 + ln;
            *(ushort4*)(out + pix*64 + mf*16 + quad*4) = o;
        }
}

// epilogue: f32 NCHW + residual from bf16 NHWC (stage 2)
static __device__ __forceinline__ void store_f(
    float* __restrict__ out, const u16* __restrict__ resid_t,
    f4 acc[4][4], int b, int th0, int tw0, int wv, int ln, int quad)
{
#pragma unroll
    for (int mf = 0; mf < 4; ++mf)
#pragma unroll
        for (int nf = 0; nf < 4; ++nf) {
            size_t pix = (size_t)b*HW_ + (th0 + wv*4 + nf)*W_ + tw0 + ln;
            ushort4 rv = *(const ushort4*)(resid_t + pix*64 + mf*16 + quad*4);
            float rr[4] = {bu2f(rv.x), bu2f(rv.y), bu2f(rv.z), bu2f(rv.w)};
#pragma unroll
            for (int r = 0; r < 4; ++r) {
                int och = mf*16 + quad*4 + r;
                out[((size_t)b*C_ + och)*HW_ + (th0 + wv*4 + nf)*W_ + tw0 + ln]
                    = acc[mf][nf][r] + rr[r];
            }
        }
}

// ---------- fused stage: gauss(inA) + convA(plain, inA) + convB(PAC, inB | guide=inA) ----------
// STAGE1: relu + bf16 NHWC outs.   STAGE2: f32 NCHW outs + residuals.
template<bool STAGE1>
__global__ __launch_bounds__(256, 2) void fused_stage(
    const u16* __restrict__ inA_t, const u16* __restrict__ inB_t,
    const u16* __restrict__ wA, const u16* __restrict__ wB,
    const float* __restrict__ biasA, const float* __restrict__ biasB,
    const u16* __restrict__ residA_t, const u16* __restrict__ residB_t,
    u16* __restrict__ outA_t, u16* __restrict__ outB_t,
    float* __restrict__ outA_f, float* __restrict__ outB_f)
{
    __shared__ u16   s_t[18*18*PITCH];   // 46656 B
    __shared__ float s_k[9*16*16];       //  9216 B  (55.9 KB total -> 2 blocks/CU)

    const int t    = threadIdx.x;
    const int b    = blockIdx.y;
    const int th0  = (blockIdx.x >> 3) * 16;
    const int tw0  = (blockIdx.x & 7) * 16;
    const int wv   = t >> 6;
    const int lane = t & 63;
    const int ln   = lane & 15;
    const int quad = lane >> 4;

    // ---- phase 1: stage guide/inA tile ----
    stage_tile(s_t, inA_t, b, th0, tw0, t);
    __syncthreads();

    // ---- phase 2a: gaussian kernel from inA tile -> s_k (one pixel per thread) ----
    {
        const int px = t & 15, py = t >> 4;
        float d2[9];
#pragma unroll
        for (int p = 0; p < 9; ++p) d2[p] = 0.f;
        const u16* cb = &s_t[((py+1)*18 + (px+1))*PITCH];
#pragma unroll 1
        for (int co = 0; co < 8; ++co) {
            s8 c8 = *(const s8*)(cb + co*8);
            float cf[8];
#pragma unroll
            for (int j = 0; j < 8; ++j) cf[j] = bu2f((u16)c8[j]);
#pragma unroll
            for (int p = 0; p < 9; ++p) {
                s8 n8 = *(const s8*)(&s_t[((py + p/3)*18 + px + p%3)*PITCH + co*8]);
#pragma unroll
                for (int j = 0; j < 8; ++j) {
                    float d = bu2f((u16)n8[j]) - cf[j];
                    d2[p] += d * d;
                }
            }
        }
#pragma unroll
        for (int p = 0; p < 9; ++p)
            s_k[p*256 + py*16 + px] = __expf(-0.5f * d2[p]);
    }

    // ---- phase 2b: convA (plain) on inA tile ----
    {
        f4 acc[4][4];
        conv_core<false>(s_t, nullptr, wA, biasA, acc, wv, ln, quad);
        if (STAGE1) store_t(outA_t, acc, b, th0, tw0, wv, ln, quad);
        else        store_f(outA_f, residA_t, acc, b, th0, tw0, wv, ln, quad);
    }

    // ---- phase 3: restage with inB tile (also orders s_k writes before reads) ----
    __syncthreads();
    stage_tile(s_t, inB_t, b, th0, tw0, t);
    __syncthreads();

    // ---- phase 4: convB (PAC with s_k) on inB tile ----
    {
        f4 acc[4][4];
        conv_core<true>(s_t, s_k, wB, biasB, acc, wv, ln, quad);
        if (STAGE1) store_t(outB_t, acc, b, th0, tw0, wv, ln, quad);
        else        store_f(outB_f, residB_t, acc, b, th0, tw0, wv, ln, quad);
    }
}

extern "C" void kernel_launch(void* const* d_in, const int* in_sizes, int n_in,
                              void* d_out, int out_size, void* d_ws, size_t ws_size,
                              hipStream_t stream)
{
    const float* x      = (const float*)d_in[0];
    const float* edge   = (const float*)d_in[1];
    const float* w_pac1 = (const float*)d_in[2];
    const float* b_pac1 = (const float*)d_in[3];
    const float* w_pac2 = (const float*)d_in[4];
    const float* b_pac2 = (const float*)d_in[5];
    const float* w_e1   = (const float*)d_in[6];
    const float* b_e1   = (const float*)d_in[7];
    const float* w_e2   = (const float*)d_in[8];
    const float* b_e2   = (const float*)d_in[9];

    float* out_sr   = (float*)d_out;
    float* out_edge = out_sr + (size_t)B_*C_*HW_;

    const size_t NT = (size_t)B_*HW_*64;
    // ws (67.4 MB): all intermediates live here — nothing parked in d_out.
    u16* x_t         = (u16*)d_ws;
    u16* edge_t      = x_t + NT;
    u16* res_edge1_t = edge_t + NT;
    u16* res_sr1_t   = res_edge1_t + NT;
    u16* w_t         = res_sr1_t + NT;    // [4][9][64][64]: 0=e1, 1=pac1, 2=e2, 3=pac2

    dim3 blk(256);

    transpose2<<<dim3(H_*8, B_, 2), blk, 0, stream>>>(x, edge, x_t, edge_t);
    wt_all<<<dim3(144, 4), blk, 0, stream>>>(w_e1, w_pac1, w_e2, w_pac2, w_t);

    // stage 1: gauss(edge)=kern1 (LDS-only) + conv_e1(edge) + pac1(x)
    fused_stage<true ><<<dim3(64, B_), blk, 0, stream>>>(
        edge_t, x_t, w_t + 0*WSZ, w_t + 1*WSZ, b_e1, b_pac1,
        nullptr, nullptr, res_edge1_t, res_sr1_t, nullptr, nullptr);
    // stage 2: gauss(res_edge1)=kern2 + conv_e2(res_edge1)+edge_resid + pac2(res_sr1)+x_resid
    fused_stage<false><<<dim3(64, B_), blk, 0, stream>>>(
        res_edge1_t, res_sr1_t, w_t + 2*WSZ, w_t + 3*WSZ, b_e2, b_pac2,
        edge_t, x_t, nullptr, nullptr, out_edge, out_sr);
}